// Round 6
// baseline (575.605 us; speedup 1.0000x reference)
//
#include <hip/hip_runtime.h>
#include <cstdint>

typedef __attribute__((ext_vector_type(8))) short bf16x8;
typedef __attribute__((ext_vector_type(4))) float f32x4;

#define B_   4
#define C_   128
#define H_   128
#define W_   128
#define HP_  130
#define WP_  130
#define O_   256
#define HW_  (H_*W_)          // 16384

// ws layout (byte offsets)
#define XPAD_BYTES   (B_*HP_*WP_*C_*2)          // bf16 xpad: 17,305,600
#define OFF_BYTE     XPAD_BYTES
#define OFF_BYTES    (B_*HW_*18*4)              // 4,718,592
#define WREPB_BYTE   (OFF_BYTE + OFF_BYTES)
#define WREPB_BYTES  (9*C_*O_*2)                // 589,824
#define STATS_BYTE   (WREPB_BYTE + WREPB_BYTES)

__device__ __forceinline__ unsigned pack_bf2(float a, float b) {
    // (bf16(b) << 16) | bf16(a), round-half-up
    unsigned ua = __builtin_bit_cast(unsigned, a) + 0x8000u;
    unsigned ub = __builtin_bit_cast(unsigned, b) + 0x8000u;
    return __builtin_amdgcn_perm(ub, ua, 0x07060302u);
}

// ---------------- K1: NCHW fp32 -> padded NHWC bf16 transpose ----------------
__global__ void k_transpose(const float* __restrict__ x, unsigned short* __restrict__ xpad) {
    __shared__ float tile[32][33];   // [c_loc][w_loc]
    int w0 = blockIdx.x * 32, c0 = blockIdx.y * 32;
    int bh = blockIdx.z;
    int b = bh >> 7, h = bh & 127;
    int tx = threadIdx.x, ty = threadIdx.y;
#pragma unroll
    for (int i = 0; i < 4; i++) {
        int c = c0 + ty + i * 8;
        tile[ty + i * 8][tx] = x[((b * C_ + c) * H_ + h) * W_ + w0 + tx];
    }
    __syncthreads();
    int tid = ty * 32 + tx;
    int cp = tid & 15;      // channel pair 0..15 -> channels 2cp, 2cp+1
    int wl = tid >> 4;      // 0..15
#pragma unroll
    for (int i = 0; i < 2; i++) {
        int wll = wl + i * 16;
        int w = w0 + wll;
        unsigned v = pack_bf2(tile[2 * cp][wll], tile[2 * cp + 1][wll]);
        *(unsigned*)(&xpad[((size_t)((b * HP_ + h + 1) * WP_ + (w + 1))) * C_ + c0 + 2 * cp]) = v;
    }
}

// ---------------- K2: offset conv v3 — LDS-staged x, full 18 j, c split over halves ----------------
__global__ __launch_bounds__(256) void k_offconv(const float* __restrict__ x,
                                                 const float* __restrict__ p_w,
                                                 const float* __restrict__ p_b,
                                                 float* __restrict__ offT) {
    __shared__ float xs[8][3][132];   // [c_local][row][col+1]; data col w at index w+1
    __shared__ float red[18][128];
    int t = threadIdx.x;
    int h = blockIdx.x;
    int b = blockIdx.y;
    int pos = t & 127;       // w
    int chalf = t >> 7;

    float acc[18];
#pragma unroll
    for (int j = 0; j < 18; j++) acc[j] = 0.f;

    for (int cc = 0; cc < 16; cc++) {
        __syncthreads();
        // stage 8 channels x 3 rows x 128 cols (float4), zero OOB rows
        for (int i = t; i < 768; i += 256) {
            int col4 = i & 31, pr = i >> 5;        // pr 0..23
            int c_l = pr & 7, row = pr >> 3;       // rows 0..2
            int hg = h + row - 1;
            float4 v = make_float4(0.f, 0.f, 0.f, 0.f);
            if ((unsigned)hg < 128u)
                v = *(const float4*)(x + (((size_t)(b * C_ + cc * 8 + c_l)) << 14) + hg * 128 + col4 * 4);
            float* d = &xs[c_l][row][1 + col4 * 4];
            d[0] = v.x; d[1] = v.y; d[2] = v.z; d[3] = v.w;
        }
        if (t < 24) {
            int c_l = t & 7, row = t >> 3;
            xs[c_l][row][0] = 0.f;
            xs[c_l][row][129] = 0.f; xs[c_l][row][130] = 0.f; xs[c_l][row][131] = 0.f;
        }
        __syncthreads();
#pragma unroll
        for (int c4 = 0; c4 < 4; c4++) {
            int c_l = chalf * 4 + c4;
            int c = cc * 8 + c_l;
            float xv[9];
#pragma unroll
            for (int kh = 0; kh < 3; kh++)
#pragma unroll
                for (int kw = 0; kw < 3; kw++)
                    xv[kh * 3 + kw] = xs[c_l][kh][pos + kw];   // col (w-1+kw) stored at w+kw
            const float* wc = p_w + c * 9;
#pragma unroll
            for (int j = 0; j < 18; j++) {
                const float* wj = wc + (size_t)j * C_ * 9;     // uniform -> scalar loads
                float a = acc[j];
#pragma unroll
                for (int tp = 0; tp < 9; tp++) a += wj[tp] * xv[tp];
                acc[j] = a;
            }
        }
    }
    // merge the two c-halves
    __syncthreads();
    if (chalf == 0) {
#pragma unroll
        for (int j = 0; j < 18; j++) red[j][pos] = acc[j];
    }
    __syncthreads();
    if (chalf == 1) {
#pragma unroll
        for (int j = 0; j < 18; j++) red[j][pos] += acc[j];
    }
    __syncthreads();
    for (int i = t; i < 18 * 128; i += 256) {
        int j = i >> 7, pp = i & 127;
        offT[((size_t)(b * 18 + j)) * HW_ + h * W_ + pp] = red[j][pp] + p_b[j];
    }
}

// ---------------- K2b: repack w_conv -> bf16 [n][kc2][ob][kq8][o128][ki8] ----------------
__global__ void k_repack(const float* __restrict__ w_conv, unsigned short* __restrict__ wrepb) {
    int i = blockIdx.x * 256 + threadIdx.x;
    if (i < 9 * C_ * O_) {
        int ki8   = i & 7;
        int o_loc = (i >> 3) & 127;
        int kq    = (i >> 10) & 7;
        int ob    = (i >> 13) & 1;
        int kc2   = (i >> 14) & 1;
        int n     = i >> 15;
        int o = ob * 128 + o_loc;
        int c = kc2 * 64 + kq * 8 + ki8;
        float f = w_conv[(o * C_ + c) * 9 + n];
        unsigned u = __builtin_bit_cast(unsigned, f);
        u += 0x7fffu + ((u >> 16) & 1u);   // RNE
        wrepb[i] = (unsigned short)(u >> 16);
    }
}

// ---------------- K3: fused gather + bf16 MFMA GEMM + BN partial sums ----------------
// grid flattened to 1024; b+4*ob = blockIdx.x % 8 pins each (b,ob) to one XCD
// (round-robin dispatch heuristic) so gathers hit a single 4.3 MB batch slice per L2.
__global__ __launch_bounds__(256, 4) void k_main(const unsigned short* __restrict__ xpad,
                                                 const float* __restrict__ offT,
                                                 const unsigned short* __restrict__ wrepb,
                                                 float* __restrict__ out,
                                                 float* __restrict__ stats) {
    __shared__ short Wl[8192];      // [kq8][o128][8]              16 KB
    __shared__ short Vl[8256];      // skewed: granule kq*129+pos  16.1 KB
    __shared__ int   pbase[4][128];
    __shared__ float pg[4][128];
    __shared__ float red[2][128];

    int t = threadIdx.x;
    int i_blk = blockIdx.x;
    int b  = i_blk & 3;
    int ob = (i_blk >> 2) & 1;
    int h  = i_blk >> 3;
    int o0 = ob * 128;
    const unsigned short* xb = xpad + (size_t)b * HP_ * WP_ * C_;

    int lane = t & 63, wv = t >> 6;
    int q = lane >> 4, l15 = lane & 15;
    int m0 = (wv & 1) * 64, n0 = (wv >> 1) * 64;
    int c8g = t & 7, posb = t >> 3;   // gather mapping: channels innermost

    f32x4 acc[4][4];
#pragma unroll
    for (int i = 0; i < 4; i++)
#pragma unroll
        for (int j = 0; j < 4; j++) acc[i][j] = (f32x4){0.f, 0.f, 0.f, 0.f};

    for (int n = 0; n < 9; n++) {
        __syncthreads();
        if (t < 128) {
            int w = t;
            float offx = offT[((size_t)(b * 18 + n)) * HW_ + h * W_ + w];
            float offy = offT[((size_t)(b * 18 + 9 + n)) * HW_ + h * W_ + w];
            int dxn = n / 3 - 1, dyn = n % 3 - 1;
            float px = (float)(h + 1 + dxn) + offx;
            float py = (float)(w + 1 + dyn) + offy;
            float pcx = fminf(fmaxf(px, 0.f), 129.f);
            float pcy = fminf(fmaxf(py, 0.f), 129.f);
            float fx = floorf(px), fy = floorf(py);
            float q0x = fminf(fmaxf(fx, 0.f), 129.f);
            float q0y = fminf(fmaxf(fy, 0.f), 129.f);
            float q1x = fminf(fmaxf(fx + 1.f, 0.f), 129.f);
            float q1y = fminf(fmaxf(fy + 1.f, 0.f), 129.f);
            float wx0 = 1.f + (q0x - pcx), wx1 = 1.f - (q1x - pcx);
            float wy0 = 1.f + (q0y - pcy), wy1 = 1.f - (q1y - pcy);
            int i0x = (int)q0x, i0y = (int)q0y, i1x = (int)q1x, i1y = (int)q1y;
            pbase[0][w] = (i0x * WP_ + i0y) * C_;
            pbase[1][w] = (i1x * WP_ + i1y) * C_;
            pbase[2][w] = (i0x * WP_ + i1y) * C_;
            pbase[3][w] = (i1x * WP_ + i0y) * C_;
            pg[0][w] = wx0 * wy0;
            pg[1][w] = wx1 * wy1;
            pg[2][w] = wx0 * wy1;
            pg[3][w] = wx1 * wy0;
        }
        for (int kc2 = 0; kc2 < 2; kc2++) {
            __syncthreads();
            // stage W chunk: 1024 granules of 16B, contiguous
            {
                const uint4* wsrc = (const uint4*)(wrepb + ((size_t)((n * 2 + kc2) * 2 + ob)) * 8192);
                uint4* wd = (uint4*)Wl;
#pragma unroll
                for (int r = 0; r < 4; r++) wd[r * 256 + t] = wsrc[r * 256 + t];
            }
            // gather V chunk: 64 ch x 128 pos, channel-contiguous lanes
            {
                int cof = kc2 * 64 + c8g * 8;
#pragma unroll
                for (int it = 0; it < 4; it++) {
                    int pos = posb + it * 32;
                    int b0 = pbase[0][pos], b1 = pbase[1][pos], b2 = pbase[2][pos], b3 = pbase[3][pos];
                    float g0 = pg[0][pos], g1 = pg[1][pos], g2 = pg[2][pos], g3 = pg[3][pos];
                    uint4 A  = *(const uint4*)(xb + b0 + cof);
                    uint4 Bv = *(const uint4*)(xb + b1 + cof);
                    uint4 Cv = *(const uint4*)(xb + b2 + cof);
                    uint4 Dv = *(const uint4*)(xb + b3 + cof);
                    unsigned outw[4];
#pragma unroll
                    for (int k = 0; k < 4; k++) {
                        unsigned ua = (&A.x)[k], ub = (&Bv.x)[k], uc = (&Cv.x)[k], ud = (&Dv.x)[k];
                        float alo = __builtin_bit_cast(float, ua << 16), ahi = __builtin_bit_cast(float, ua & 0xffff0000u);
                        float blo = __builtin_bit_cast(float, ub << 16), bhi = __builtin_bit_cast(float, ub & 0xffff0000u);
                        float clo = __builtin_bit_cast(float, uc << 16), chi = __builtin_bit_cast(float, uc & 0xffff0000u);
                        float dlo = __builtin_bit_cast(float, ud << 16), dhi = __builtin_bit_cast(float, ud & 0xffff0000u);
                        float vlo = g0 * alo + g1 * blo + g2 * clo + g3 * dlo;
                        float vhi = g0 * ahi + g1 * bhi + g2 * chi + g3 * dhi;
                        outw[k] = pack_bf2(vlo, vhi);
                    }
                    *(uint4*)&Vl[(size_t)(c8g * 129 + pos) * 8] = make_uint4(outw[0], outw[1], outw[2], outw[3]);
                }
            }
            __syncthreads();
            // MFMA: K=64 chunk = 2 K-steps of 32
            {
                const bf16x8* Af = (const bf16x8*)Wl;
                const bf16x8* Bf = (const bf16x8*)Vl;
#pragma unroll
                for (int ks = 0; ks < 2; ks++) {
                    int kq = ks * 4 + q;
                    bf16x8 av[4], bv[4];
#pragma unroll
                    for (int i = 0; i < 4; i++) av[i] = Af[kq * 128 + m0 + i * 16 + l15];
#pragma unroll
                    for (int j = 0; j < 4; j++) bv[j] = Bf[kq * 129 + n0 + j * 16 + l15];
#pragma unroll
                    for (int i = 0; i < 4; i++)
#pragma unroll
                        for (int j = 0; j < 4; j++)
                            acc[i][j] = __builtin_amdgcn_mfma_f32_16x16x32_bf16(av[i], bv[j], acc[i][j], 0, 0, 0);
                }
            }
        }
    }

    // epilogue: write out + BN partial sums
    __syncthreads();
    if (t < 128) { red[0][t] = 0.f; red[1][t] = 0.f; }
    __syncthreads();
    float* outb = out + ((size_t)(b * O_ + o0)) * HW_ + h * W_;
#pragma unroll
    for (int i = 0; i < 4; i++) {
#pragma unroll
        for (int r = 0; r < 4; r++) {
            int o_loc = m0 + i * 16 + q * 4 + r;
            float s = 0.f, s2 = 0.f;
#pragma unroll
            for (int j = 0; j < 4; j++) {
                float v = acc[i][j][r];
                s += v; s2 += v * v;
                outb[(size_t)o_loc * HW_ + n0 + j * 16 + l15] = v;
            }
            s  += __shfl_xor(s, 1);  s  += __shfl_xor(s, 2);  s  += __shfl_xor(s, 4);  s  += __shfl_xor(s, 8);
            s2 += __shfl_xor(s2, 1); s2 += __shfl_xor(s2, 2); s2 += __shfl_xor(s2, 4); s2 += __shfl_xor(s2, 8);
            if (l15 == 0) {
                atomicAdd(&red[0][o_loc], s);
                atomicAdd(&red[1][o_loc], s2);
            }
        }
    }
    __syncthreads();
    if (t < 128) {
        atomicAdd(&stats[o0 + t], red[0][t]);
        atomicAdd(&stats[256 + o0 + t], red[1][t]);
    }
}

// ---------------- K4: BN stats finalize ----------------
__global__ void k_bnstats(float* __restrict__ stats,
                          const float* __restrict__ gamma,
                          const float* __restrict__ beta) {
    int t = threadIdx.x;  // 256
    float s = stats[t], s2 = stats[256 + t];
    float mean = s * (1.f / 65536.f);
    float var = s2 * (1.f / 65536.f) - mean * mean;
    float sc = gamma[t] * rsqrtf(var + 1e-5f);
    float sh = beta[t] - mean * sc;
    stats[512 + t] = sc;
    stats[768 + t] = sh;
}

// ---------------- K5: normalize + leaky ReLU (in-place on d_out) ----------------
__global__ __launch_bounds__(256) void k_apply(float* __restrict__ out,
                                               const float* __restrict__ stats) {
    int idx = blockIdx.x * 256 + threadIdx.x;
    int e = idx * 4;
    int o = (e >> 14) & 255;
    float sc = stats[512 + o], sh = stats[768 + o];
    float4 v = *(float4*)(out + e);
    v.x = v.x * sc + sh; v.x = (v.x >= 0.f) ? v.x : 0.1f * v.x;
    v.y = v.y * sc + sh; v.y = (v.y >= 0.f) ? v.y : 0.1f * v.y;
    v.z = v.z * sc + sh; v.z = (v.z >= 0.f) ? v.z : 0.1f * v.z;
    v.w = v.w * sc + sh; v.w = (v.w >= 0.f) ? v.w : 0.1f * v.w;
    *(float4*)(out + e) = v;
}

extern "C" void kernel_launch(void* const* d_in, const int* in_sizes, int n_in,
                              void* d_out, int out_size, void* d_ws, size_t ws_size,
                              hipStream_t stream) {
    const float* x      = (const float*)d_in[0];
    const float* p_w    = (const float*)d_in[1];
    const float* p_b    = (const float*)d_in[2];
    const float* w_conv = (const float*)d_in[3];
    const float* gamma  = (const float*)d_in[4];
    const float* beta   = (const float*)d_in[5];
    float* out = (float*)d_out;

    char* wsb = (char*)d_ws;
    unsigned short* xpad  = (unsigned short*)wsb;
    float*          offT  = (float*)(wsb + OFF_BYTE);
    unsigned short* wrepb = (unsigned short*)(wsb + WREPB_BYTE);
    float*          stats = (float*)(wsb + STATS_BYTE);

    hipMemsetAsync(xpad, 0, (size_t)XPAD_BYTES, stream);
    hipMemsetAsync(stats, 0, 4096, stream);

    k_transpose<<<dim3(W_ / 32, C_ / 32, B_ * H_), dim3(32, 8), 0, stream>>>(x, xpad);
    k_offconv<<<dim3(H_, B_), 256, 0, stream>>>(x, p_w, p_b, offT);
    k_repack<<<dim3((9 * C_ * O_ + 255) / 256), 256, 0, stream>>>(w_conv, wrepb);
    k_main<<<dim3(1024), 256, 0, stream>>>(xpad, offT, wrepb, out, stats);
    k_bnstats<<<1, 256, 0, stream>>>(stats, gamma, beta);
    k_apply<<<dim3(16384), 256, 0, stream>>>(out, stats);
}

// Round 7
// 305.346 us; speedup vs baseline: 1.8851x; 1.8851x over previous
//
#include <hip/hip_runtime.h>
#include <cstdint>

typedef __attribute__((ext_vector_type(8))) short bf16x8;
typedef __attribute__((ext_vector_type(4))) float f32x4;

#define B_   4
#define C_   128
#define H_   128
#define W_   128
#define HP_  130
#define WP_  130
#define O_   256
#define HW_  (H_*W_)          // 16384

// ws layout (byte offsets)
#define XPAD_BYTES   (B_*HP_*WP_*C_*2)          // bf16 xpad: 17,305,600
#define OFF_BYTE     XPAD_BYTES
#define OFF_BYTES    (B_*HW_*18*4)              // 4,718,592
#define WREPB_BYTE   (OFF_BYTE + OFF_BYTES)
#define WREPB_BYTES  (9*C_*O_*2)                // 589,824
#define STATS_BYTE   (WREPB_BYTE + WREPB_BYTES)
#define WOFF_BYTE    (STATS_BYTE + 4096)
#define WOFF_BYTES   (9*4*4*32*8*2)             // 73,728

__device__ __forceinline__ unsigned pack_bf2(float a, float b) {
    // (bf16(b) << 16) | bf16(a), round-half-up
    unsigned ua = __builtin_bit_cast(unsigned, a) + 0x8000u;
    unsigned ub = __builtin_bit_cast(unsigned, b) + 0x8000u;
    return __builtin_amdgcn_perm(ub, ua, 0x07060302u);
}

// ---------------- K1: NCHW fp32 -> padded NHWC bf16 transpose ----------------
__global__ void k_transpose(const float* __restrict__ x, unsigned short* __restrict__ xpad) {
    __shared__ float tile[32][33];   // [c_loc][w_loc]
    int w0 = blockIdx.x * 32, c0 = blockIdx.y * 32;
    int bh = blockIdx.z;
    int b = bh >> 7, h = bh & 127;
    int tx = threadIdx.x, ty = threadIdx.y;
#pragma unroll
    for (int i = 0; i < 4; i++) {
        int c = c0 + ty + i * 8;
        tile[ty + i * 8][tx] = x[((b * C_ + c) * H_ + h) * W_ + w0 + tx];
    }
    __syncthreads();
    int tid = ty * 32 + tx;
    int cp = tid & 15;      // channel pair 0..15 -> channels 2cp, 2cp+1
    int wl = tid >> 4;      // 0..15
#pragma unroll
    for (int i = 0; i < 2; i++) {
        int wll = wl + i * 16;
        int w = w0 + wll;
        unsigned v = pack_bf2(tile[2 * cp][wll], tile[2 * cp + 1][wll]);
        *(unsigned*)(&xpad[((size_t)((b * HP_ + h + 1) * WP_ + (w + 1))) * C_ + c0 + 2 * cp]) = v;
    }
}

// ---------------- K2a: repack p_w -> bf16 A-fragments [tap][kc][q][m32][e8], m>=18 zero ----------------
__global__ void k_repack2(const float* __restrict__ p_w, short* __restrict__ wofff) {
    int i = blockIdx.x * 256 + threadIdx.x;  // 36864 total
    if (i < 9 * 4096) {
        int e = i & 7, m = (i >> 3) & 31, q = (i >> 8) & 3, kc = (i >> 10) & 3, tap = i >> 12;
        float f = (m < 18) ? p_w[((size_t)m * C_ + kc * 32 + q * 8 + e) * 9 + tap] : 0.f;
        unsigned u = __builtin_bit_cast(unsigned, f);
        u += 0x7fffu + ((u >> 16) & 1u);   // RNE
        wofff[i] = (short)(u >> 16);
    }
}

// ---------------- K2: offset conv as MFMA GEMM (M=18 pad 32, K=1152), no LDS/barriers ----------------
__global__ __launch_bounds__(256) void k_offconv(const unsigned short* __restrict__ xpad,
                                                 const short* __restrict__ wofff,
                                                 const float* __restrict__ p_b,
                                                 float* __restrict__ offT) {
    int t = threadIdx.x;
    int ph = blockIdx.x;   // pos half 0/1
    int h  = blockIdx.y;
    int b  = blockIdx.z;
    const unsigned short* xb = xpad + (size_t)b * HP_ * WP_ * C_;
    int lane = t & 63, wv = t >> 6;
    int q = lane >> 4, l15 = lane & 15;
    int pos0 = ph * 64 + wv * 16;
    int poscol = pos0 + l15;

    f32x4 accA = {0.f, 0.f, 0.f, 0.f}, accB = {0.f, 0.f, 0.f, 0.f};
    const bf16x8* Wf = (const bf16x8*)wofff;

    for (int tap = 0; tap < 9; tap++) {
        int row = h + tap / 3;           // padded-row index (zero rows give conv pad)
        int col = poscol + tap % 3;      // padded-col index
        const unsigned short* src = xb + ((size_t)(row * WP_ + col)) * C_ + q * 8;
#pragma unroll
        for (int kc = 0; kc < 4; kc++) {
            bf16x8 a0 = Wf[(size_t)(((tap * 4 + kc) * 4 + q) * 32) + l15];
            bf16x8 a1 = Wf[(size_t)(((tap * 4 + kc) * 4 + q) * 32) + 16 + l15];
            bf16x8 bv = *(const bf16x8*)(src + kc * 32);
            accA = __builtin_amdgcn_mfma_f32_16x16x32_bf16(a0, bv, accA, 0, 0, 0);
            accB = __builtin_amdgcn_mfma_f32_16x16x32_bf16(a1, bv, accB, 0, 0, 0);
        }
    }
    size_t hw = (size_t)h * W_ + pos0 + l15;
#pragma unroll
    for (int r = 0; r < 4; r++) {
        int j = q * 4 + r;
        offT[((size_t)(b * 18 + j)) * HW_ + hw] = accA[r] + p_b[j];
    }
    if (q == 0) {
#pragma unroll
        for (int r = 0; r < 2; r++) {
            int j = 16 + r;
            offT[((size_t)(b * 18 + j)) * HW_ + hw] = accB[r] + p_b[j];
        }
    }
}

// ---------------- K2b: repack w_conv -> bf16 [n][kc2][ob][kq8][o128][ki8] ----------------
__global__ void k_repack(const float* __restrict__ w_conv, unsigned short* __restrict__ wrepb) {
    int i = blockIdx.x * 256 + threadIdx.x;
    if (i < 9 * C_ * O_) {
        int ki8   = i & 7;
        int o_loc = (i >> 3) & 127;
        int kq    = (i >> 10) & 7;
        int ob    = (i >> 13) & 1;
        int kc2   = (i >> 14) & 1;
        int n     = i >> 15;
        int o = ob * 128 + o_loc;
        int c = kc2 * 64 + kq * 8 + ki8;
        float f = w_conv[(o * C_ + c) * 9 + n];
        unsigned u = __builtin_bit_cast(unsigned, f);
        u += 0x7fffu + ((u >> 16) & 1u);   // RNE
        wrepb[i] = (unsigned short)(u >> 16);
    }
}

// ---------------- K3: fused gather + bf16 MFMA GEMM + BN partial sums ----------------
__global__ __launch_bounds__(256, 4) void k_main(const unsigned short* __restrict__ xpad,
                                                 const float* __restrict__ offT,
                                                 const unsigned short* __restrict__ wrepb,
                                                 float* __restrict__ out,
                                                 float* __restrict__ stats) {
    __shared__ short Wl[8192];      // [kq8][o128][8]              16 KB
    __shared__ short Vl[8256];      // skewed: granule kq*129+pos  16.1 KB
    __shared__ int   pbase[4][128];
    __shared__ float pg[4][128];
    __shared__ float red[2][128];

    int t = threadIdx.x;
    int i_blk = blockIdx.x;
    int b  = i_blk & 3;
    int ob = (i_blk >> 2) & 1;
    int h  = i_blk >> 3;
    int o0 = ob * 128;
    const unsigned short* xb = xpad + (size_t)b * HP_ * WP_ * C_;

    int lane = t & 63, wv = t >> 6;
    int q = lane >> 4, l15 = lane & 15;
    int m0 = (wv & 1) * 64, n0 = (wv >> 1) * 64;
    int c8g = t & 7, posb = t >> 3;   // gather mapping: channels innermost

    f32x4 acc[4][4];
#pragma unroll
    for (int i = 0; i < 4; i++)
#pragma unroll
        for (int j = 0; j < 4; j++) acc[i][j] = (f32x4){0.f, 0.f, 0.f, 0.f};

    for (int n = 0; n < 9; n++) {
        __syncthreads();
        if (t < 128) {
            int w = t;
            float offx = offT[((size_t)(b * 18 + n)) * HW_ + h * W_ + w];
            float offy = offT[((size_t)(b * 18 + 9 + n)) * HW_ + h * W_ + w];
            int dxn = n / 3 - 1, dyn = n % 3 - 1;
            float px = (float)(h + 1 + dxn) + offx;
            float py = (float)(w + 1 + dyn) + offy;
            float pcx = fminf(fmaxf(px, 0.f), 129.f);
            float pcy = fminf(fmaxf(py, 0.f), 129.f);
            float fx = floorf(px), fy = floorf(py);
            float q0x = fminf(fmaxf(fx, 0.f), 129.f);
            float q0y = fminf(fmaxf(fy, 0.f), 129.f);
            float q1x = fminf(fmaxf(fx + 1.f, 0.f), 129.f);
            float q1y = fminf(fmaxf(fy + 1.f, 0.f), 129.f);
            float wx0 = 1.f + (q0x - pcx), wx1 = 1.f - (q1x - pcx);
            float wy0 = 1.f + (q0y - pcy), wy1 = 1.f - (q1y - pcy);
            int i0x = (int)q0x, i0y = (int)q0y, i1x = (int)q1x, i1y = (int)q1y;
            pbase[0][w] = (i0x * WP_ + i0y) * C_;
            pbase[1][w] = (i1x * WP_ + i1y) * C_;
            pbase[2][w] = (i0x * WP_ + i1y) * C_;
            pbase[3][w] = (i1x * WP_ + i0y) * C_;
            pg[0][w] = wx0 * wy0;
            pg[1][w] = wx1 * wy1;
            pg[2][w] = wx0 * wy1;
            pg[3][w] = wx1 * wy0;
        }
        for (int kc2 = 0; kc2 < 2; kc2++) {
            __syncthreads();
            // stage W chunk: 1024 granules of 16B, contiguous
            {
                const uint4* wsrc = (const uint4*)(wrepb + ((size_t)((n * 2 + kc2) * 2 + ob)) * 8192);
                uint4* wd = (uint4*)Wl;
#pragma unroll
                for (int r = 0; r < 4; r++) wd[r * 256 + t] = wsrc[r * 256 + t];
            }
            // gather V chunk: 64 ch x 128 pos, channel-contiguous lanes
            {
                int cof = kc2 * 64 + c8g * 8;
#pragma unroll
                for (int it = 0; it < 4; it++) {
                    int pos = posb + it * 32;
                    int b0 = pbase[0][pos], b1 = pbase[1][pos], b2 = pbase[2][pos], b3 = pbase[3][pos];
                    float g0 = pg[0][pos], g1 = pg[1][pos], g2 = pg[2][pos], g3 = pg[3][pos];
                    uint4 A  = *(const uint4*)(xb + b0 + cof);
                    uint4 Bv = *(const uint4*)(xb + b1 + cof);
                    uint4 Cv = *(const uint4*)(xb + b2 + cof);
                    uint4 Dv = *(const uint4*)(xb + b3 + cof);
                    unsigned outw[4];
#pragma unroll
                    for (int k = 0; k < 4; k++) {
                        unsigned ua = (&A.x)[k], ub = (&Bv.x)[k], uc = (&Cv.x)[k], ud = (&Dv.x)[k];
                        float alo = __builtin_bit_cast(float, ua << 16), ahi = __builtin_bit_cast(float, ua & 0xffff0000u);
                        float blo = __builtin_bit_cast(float, ub << 16), bhi = __builtin_bit_cast(float, ub & 0xffff0000u);
                        float clo = __builtin_bit_cast(float, uc << 16), chi = __builtin_bit_cast(float, uc & 0xffff0000u);
                        float dlo = __builtin_bit_cast(float, ud << 16), dhi = __builtin_bit_cast(float, ud & 0xffff0000u);
                        float vlo = g0 * alo + g1 * blo + g2 * clo + g3 * dlo;
                        float vhi = g0 * ahi + g1 * bhi + g2 * chi + g3 * dhi;
                        outw[k] = pack_bf2(vlo, vhi);
                    }
                    *(uint4*)&Vl[(size_t)(c8g * 129 + pos) * 8] = make_uint4(outw[0], outw[1], outw[2], outw[3]);
                }
            }
            __syncthreads();
            // MFMA: K=64 chunk = 2 K-steps of 32
            {
                const bf16x8* Af = (const bf16x8*)Wl;
                const bf16x8* Bf = (const bf16x8*)Vl;
#pragma unroll
                for (int ks = 0; ks < 2; ks++) {
                    int kq = ks * 4 + q;
                    bf16x8 av[4], bv[4];
#pragma unroll
                    for (int i = 0; i < 4; i++) av[i] = Af[kq * 128 + m0 + i * 16 + l15];
#pragma unroll
                    for (int j = 0; j < 4; j++) bv[j] = Bf[kq * 129 + n0 + j * 16 + l15];
#pragma unroll
                    for (int i = 0; i < 4; i++)
#pragma unroll
                        for (int j = 0; j < 4; j++)
                            acc[i][j] = __builtin_amdgcn_mfma_f32_16x16x32_bf16(av[i], bv[j], acc[i][j], 0, 0, 0);
                }
            }
        }
    }

    // epilogue: write out + BN partial sums
    __syncthreads();
    if (t < 128) { red[0][t] = 0.f; red[1][t] = 0.f; }
    __syncthreads();
    float* outb = out + ((size_t)(b * O_ + o0)) * HW_ + h * W_;
#pragma unroll
    for (int i = 0; i < 4; i++) {
#pragma unroll
        for (int r = 0; r < 4; r++) {
            int o_loc = m0 + i * 16 + q * 4 + r;
            float s = 0.f, s2 = 0.f;
#pragma unroll
            for (int j = 0; j < 4; j++) {
                float v = acc[i][j][r];
                s += v; s2 += v * v;
                outb[(size_t)o_loc * HW_ + n0 + j * 16 + l15] = v;
            }
            s  += __shfl_xor(s, 1);  s  += __shfl_xor(s, 2);  s  += __shfl_xor(s, 4);  s  += __shfl_xor(s, 8);
            s2 += __shfl_xor(s2, 1); s2 += __shfl_xor(s2, 2); s2 += __shfl_xor(s2, 4); s2 += __shfl_xor(s2, 8);
            if (l15 == 0) {
                atomicAdd(&red[0][o_loc], s);
                atomicAdd(&red[1][o_loc], s2);
            }
        }
    }
    __syncthreads();
    if (t < 128) {
        atomicAdd(&stats[o0 + t], red[0][t]);
        atomicAdd(&stats[256 + o0 + t], red[1][t]);
    }
}

// ---------------- K4: BN stats finalize ----------------
__global__ void k_bnstats(float* __restrict__ stats,
                          const float* __restrict__ gamma,
                          const float* __restrict__ beta) {
    int t = threadIdx.x;  // 256
    float s = stats[t], s2 = stats[256 + t];
    float mean = s * (1.f / 65536.f);
    float var = s2 * (1.f / 65536.f) - mean * mean;
    float sc = gamma[t] * rsqrtf(var + 1e-5f);
    float sh = beta[t] - mean * sc;
    stats[512 + t] = sc;
    stats[768 + t] = sh;
}

// ---------------- K5: normalize + leaky ReLU (in-place on d_out) ----------------
__global__ __launch_bounds__(256) void k_apply(float* __restrict__ out,
                                               const float* __restrict__ stats) {
    int idx = blockIdx.x * 256 + threadIdx.x;
    int e = idx * 4;
    int o = (e >> 14) & 255;
    float sc = stats[512 + o], sh = stats[768 + o];
    float4 v = *(float4*)(out + e);
    v.x = v.x * sc + sh; v.x = (v.x >= 0.f) ? v.x : 0.1f * v.x;
    v.y = v.y * sc + sh; v.y = (v.y >= 0.f) ? v.y : 0.1f * v.y;
    v.z = v.z * sc + sh; v.z = (v.z >= 0.f) ? v.z : 0.1f * v.z;
    v.w = v.w * sc + sh; v.w = (v.w >= 0.f) ? v.w : 0.1f * v.w;
    *(float4*)(out + e) = v;
}

extern "C" void kernel_launch(void* const* d_in, const int* in_sizes, int n_in,
                              void* d_out, int out_size, void* d_ws, size_t ws_size,
                              hipStream_t stream) {
    const float* x      = (const float*)d_in[0];
    const float* p_w    = (const float*)d_in[1];
    const float* p_b    = (const float*)d_in[2];
    const float* w_conv = (const float*)d_in[3];
    const float* gamma  = (const float*)d_in[4];
    const float* beta   = (const float*)d_in[5];
    float* out = (float*)d_out;

    char* wsb = (char*)d_ws;
    unsigned short* xpad  = (unsigned short*)wsb;
    float*          offT  = (float*)(wsb + OFF_BYTE);
    unsigned short* wrepb = (unsigned short*)(wsb + WREPB_BYTE);
    float*          stats = (float*)(wsb + STATS_BYTE);
    short*          wofff = (short*)(wsb + WOFF_BYTE);

    hipMemsetAsync(xpad, 0, (size_t)XPAD_BYTES, stream);
    hipMemsetAsync(stats, 0, 4096, stream);

    k_transpose<<<dim3(W_ / 32, C_ / 32, B_ * H_), dim3(32, 8), 0, stream>>>(x, xpad);
    k_repack2<<<dim3(144), 256, 0, stream>>>(p_w, wofff);
    k_offconv<<<dim3(2, H_, B_), 256, 0, stream>>>(xpad, wofff, p_b, offT);
    k_repack<<<dim3((9 * C_ * O_ + 255) / 256), 256, 0, stream>>>(w_conv, wrepb);
    k_main<<<dim3(1024), 256, 0, stream>>>(xpad, offT, wrepb, out, stats);
    k_bnstats<<<1, 256, 0, stream>>>(stats, gamma, beta);
    k_apply<<<dim3(16384), 256, 0, stream>>>(out, stats);
}

// Round 8
// 238.129 us; speedup vs baseline: 2.4172x; 1.2823x over previous
//
#include <hip/hip_runtime.h>
#include <cstdint>

typedef __attribute__((ext_vector_type(8))) short bf16x8;
typedef __attribute__((ext_vector_type(4))) float f32x4;

#define B_   4
#define C_   128
#define H_   128
#define W_   128
#define HP_  130
#define WP_  130
#define O_   256
#define HW_  (H_*W_)          // 16384

// ws layout (byte offsets)
#define XPAD_BYTES   (B_*HP_*WP_*C_*2)          // bf16 xpad: 17,305,600
#define OFF_BYTE     XPAD_BYTES
#define OFF_BYTES    (B_*HW_*18*4)              // 4,718,592
#define WREPB_BYTE   (OFF_BYTE + OFF_BYTES)
#define WREPB_BYTES  (9*C_*O_*2)                // 589,824
#define STATS_BYTE   (WREPB_BYTE + WREPB_BYTES)
#define WOFF_BYTE    (STATS_BYTE + 4096)
#define WOFF_BYTES   (9*4*4*32*8*2)             // 73,728

__device__ __forceinline__ unsigned pack_bf2(float a, float b) {
    unsigned ua = __builtin_bit_cast(unsigned, a) + 0x8000u;
    unsigned ub = __builtin_bit_cast(unsigned, b) + 0x8000u;
    return __builtin_amdgcn_perm(ub, ua, 0x07060302u);
}

// ---------------- K1: NCHW fp32 -> padded NHWC bf16 transpose ----------------
__global__ void k_transpose(const float* __restrict__ x, unsigned short* __restrict__ xpad) {
    __shared__ float tile[32][33];   // [c_loc][w_loc]
    int w0 = blockIdx.x * 32, c0 = blockIdx.y * 32;
    int bh = blockIdx.z;
    int b = bh >> 7, h = bh & 127;
    int tx = threadIdx.x, ty = threadIdx.y;
#pragma unroll
    for (int i = 0; i < 4; i++) {
        int c = c0 + ty + i * 8;
        tile[ty + i * 8][tx] = x[((b * C_ + c) * H_ + h) * W_ + w0 + tx];
    }
    __syncthreads();
    int tid = ty * 32 + tx;
    int cp = tid & 15;
    int wl = tid >> 4;
#pragma unroll
    for (int i = 0; i < 2; i++) {
        int wll = wl + i * 16;
        int w = w0 + wll;
        unsigned v = pack_bf2(tile[2 * cp][wll], tile[2 * cp + 1][wll]);
        *(unsigned*)(&xpad[((size_t)((b * HP_ + h + 1) * WP_ + (w + 1))) * C_ + c0 + 2 * cp]) = v;
    }
}

// ---------------- K2a: repack p_w -> bf16 A-fragments [tap][kc][q][m32][e8], m>=18 zero ----------------
__global__ void k_repack2(const float* __restrict__ p_w, short* __restrict__ wofff) {
    int i = blockIdx.x * 256 + threadIdx.x;
    if (i < 9 * 4096) {
        int e = i & 7, m = (i >> 3) & 31, q = (i >> 8) & 3, kc = (i >> 10) & 3, tap = i >> 12;
        float f = (m < 18) ? p_w[((size_t)m * C_ + kc * 32 + q * 8 + e) * 9 + tap] : 0.f;
        unsigned u = __builtin_bit_cast(unsigned, f);
        u += 0x7fffu + ((u >> 16) & 1u);   // RNE
        wofff[i] = (short)(u >> 16);
    }
}

// ---------------- K2: offset conv as MFMA GEMM (M=18 pad 32, K=1152) ----------------
__global__ __launch_bounds__(256) void k_offconv(const unsigned short* __restrict__ xpad,
                                                 const short* __restrict__ wofff,
                                                 const float* __restrict__ p_b,
                                                 float* __restrict__ offT) {
    int t = threadIdx.x;
    int ph = blockIdx.x;
    int h  = blockIdx.y;
    int b  = blockIdx.z;
    const unsigned short* xb = xpad + (size_t)b * HP_ * WP_ * C_;
    int lane = t & 63, wv = t >> 6;
    int q = lane >> 4, l15 = lane & 15;
    int pos0 = ph * 64 + wv * 16;
    int poscol = pos0 + l15;

    f32x4 accA = {0.f, 0.f, 0.f, 0.f}, accB = {0.f, 0.f, 0.f, 0.f};
    const bf16x8* Wf = (const bf16x8*)wofff;

    for (int tap = 0; tap < 9; tap++) {
        int row = h + tap / 3;
        int col = poscol + tap % 3;
        const unsigned short* src = xb + ((size_t)(row * WP_ + col)) * C_ + q * 8;
#pragma unroll
        for (int kc = 0; kc < 4; kc++) {
            bf16x8 a0 = Wf[(size_t)(((tap * 4 + kc) * 4 + q) * 32) + l15];
            bf16x8 a1 = Wf[(size_t)(((tap * 4 + kc) * 4 + q) * 32) + 16 + l15];
            bf16x8 bv = *(const bf16x8*)(src + kc * 32);
            accA = __builtin_amdgcn_mfma_f32_16x16x32_bf16(a0, bv, accA, 0, 0, 0);
            accB = __builtin_amdgcn_mfma_f32_16x16x32_bf16(a1, bv, accB, 0, 0, 0);
        }
    }
    size_t hw = (size_t)h * W_ + pos0 + l15;
#pragma unroll
    for (int r = 0; r < 4; r++) {
        int j = q * 4 + r;
        offT[((size_t)(b * 18 + j)) * HW_ + hw] = accA[r] + p_b[j];
    }
    if (q == 0) {
#pragma unroll
        for (int r = 0; r < 2; r++) {
            int j = 16 + r;
            offT[((size_t)(b * 18 + j)) * HW_ + hw] = accB[r] + p_b[j];
        }
    }
}

// ---------------- K2b: repack w_conv -> bf16 [n][kc4][kq4][o256][ki8] ----------------
__global__ void k_repack(const float* __restrict__ w_conv, unsigned short* __restrict__ wrepb) {
    int i = blockIdx.x * 256 + threadIdx.x;
    if (i < 9 * C_ * O_) {
        int ki8 = i & 7;
        int o   = (i >> 3) & 255;
        int kq  = (i >> 11) & 3;
        int kc  = (i >> 13) & 3;
        int n   = i >> 15;
        int c = kc * 32 + kq * 8 + ki8;
        float f = w_conv[(o * C_ + c) * 9 + n];
        unsigned u = __builtin_bit_cast(unsigned, f);
        u += 0x7fffu + ((u >> 16) & 1u);   // RNE
        wrepb[i] = (unsigned short)(u >> 16);
    }
}

// ---------------- K3: one block per (b,h): full 256-o tile; gather shared, LDS-staged C ----------------
__global__ __launch_bounds__(512, 4) void k_main(const unsigned short* __restrict__ xpad,
                                                 const float* __restrict__ offT,
                                                 const unsigned short* __restrict__ wrepb,
                                                 float* __restrict__ out,
                                                 float* __restrict__ stats) {
    __shared__ short Wl[8192];        // [kq4][o256][8]  16 KB
    __shared__ short Vl[4128];        // skewed [kq4][pos 129][8]  8.06 KB
    __shared__ int   pbase[4][128];
    __shared__ float pg[4][128];
    __shared__ float red0[256], red1[256];
    __shared__ float slab[64 * 132];  // 33.8 KB C-staging

    int t = threadIdx.x;
    int i_blk = blockIdx.x;
    int b = i_blk & 3;                // XCD k serves b = k&3 only (round-robin heuristic)
    int h = i_blk >> 2;
    const unsigned short* xb = xpad + (size_t)b * HP_ * WP_ * C_;

    int lane = t & 63, wv = t >> 6;   // 8 waves
    int q = lane >> 4, l15 = lane & 15;
    int m0 = (wv & 3) * 64;           // o-slice
    int ph = wv >> 2;                 // pos half
    int n0 = ph * 64;
    int c4g = t & 3, posb = t >> 2;   // gather: 4 ch-subquads x 128 pos

    f32x4 acc[4][4];
#pragma unroll
    for (int i = 0; i < 4; i++)
#pragma unroll
        for (int j = 0; j < 4; j++) acc[i][j] = (f32x4){0.f, 0.f, 0.f, 0.f};

    for (int n = 0; n < 9; n++) {
        __syncthreads();
        if (t < 128) {
            int w = t;
            float offx = offT[((size_t)(b * 18 + n)) * HW_ + h * W_ + w];
            float offy = offT[((size_t)(b * 18 + 9 + n)) * HW_ + h * W_ + w];
            int dxn = n / 3 - 1, dyn = n % 3 - 1;
            float px = (float)(h + 1 + dxn) + offx;
            float py = (float)(w + 1 + dyn) + offy;
            float pcx = fminf(fmaxf(px, 0.f), 129.f);
            float pcy = fminf(fmaxf(py, 0.f), 129.f);
            float fx = floorf(px), fy = floorf(py);
            float q0x = fminf(fmaxf(fx, 0.f), 129.f);
            float q0y = fminf(fmaxf(fy, 0.f), 129.f);
            float q1x = fminf(fmaxf(fx + 1.f, 0.f), 129.f);
            float q1y = fminf(fmaxf(fy + 1.f, 0.f), 129.f);
            float wx0 = 1.f + (q0x - pcx), wx1 = 1.f - (q1x - pcx);
            float wy0 = 1.f + (q0y - pcy), wy1 = 1.f - (q1y - pcy);
            int i0x = (int)q0x, i0y = (int)q0y, i1x = (int)q1x, i1y = (int)q1y;
            pbase[0][w] = (i0x * WP_ + i0y) * C_;
            pbase[1][w] = (i1x * WP_ + i1y) * C_;
            pbase[2][w] = (i0x * WP_ + i1y) * C_;
            pbase[3][w] = (i1x * WP_ + i0y) * C_;
            pg[0][w] = wx0 * wy0;
            pg[1][w] = wx1 * wy1;
            pg[2][w] = wx0 * wy1;
            pg[3][w] = wx1 * wy0;
        }
        for (int kc = 0; kc < 4; kc++) {
            __syncthreads();
            // stage W chunk: 1024 granules of 16B
            {
                const uint4* wsrc = (const uint4*)(wrepb + ((size_t)(n * 4 + kc)) * 8192);
                uint4* wd = (uint4*)Wl;
                wd[t] = wsrc[t];
                wd[t + 512] = wsrc[t + 512];
            }
            // gather V chunk: 32 ch x 128 pos (each pos+8ch per thread)
            {
                int cof = kc * 32 + c4g * 8;
                int b0 = pbase[0][posb], b1 = pbase[1][posb], b2 = pbase[2][posb], b3 = pbase[3][posb];
                float g0 = pg[0][posb], g1 = pg[1][posb], g2 = pg[2][posb], g3 = pg[3][posb];
                uint4 A  = *(const uint4*)(xb + b0 + cof);
                uint4 Bv = *(const uint4*)(xb + b1 + cof);
                uint4 Cv = *(const uint4*)(xb + b2 + cof);
                uint4 Dv = *(const uint4*)(xb + b3 + cof);
                unsigned outw[4];
#pragma unroll
                for (int k = 0; k < 4; k++) {
                    unsigned ua = (&A.x)[k], ub = (&Bv.x)[k], uc = (&Cv.x)[k], ud = (&Dv.x)[k];
                    float alo = __builtin_bit_cast(float, ua << 16), ahi = __builtin_bit_cast(float, ua & 0xffff0000u);
                    float blo = __builtin_bit_cast(float, ub << 16), bhi = __builtin_bit_cast(float, ub & 0xffff0000u);
                    float clo = __builtin_bit_cast(float, uc << 16), chi = __builtin_bit_cast(float, uc & 0xffff0000u);
                    float dlo = __builtin_bit_cast(float, ud << 16), dhi = __builtin_bit_cast(float, ud & 0xffff0000u);
                    float vlo = g0 * alo + g1 * blo + g2 * clo + g3 * dlo;
                    float vhi = g0 * ahi + g1 * bhi + g2 * chi + g3 * dhi;
                    outw[k] = pack_bf2(vlo, vhi);
                }
                *(uint4*)&Vl[(size_t)(c4g * 129 + posb) * 8] = make_uint4(outw[0], outw[1], outw[2], outw[3]);
            }
            __syncthreads();
            // one K=32 MFMA step: 16 MFMAs per wave
            {
                const bf16x8* Af = (const bf16x8*)Wl;
                const bf16x8* Bf = (const bf16x8*)Vl;
                bf16x8 av[4];
#pragma unroll
                for (int i = 0; i < 4; i++) av[i] = Af[q * 256 + m0 + i * 16 + l15];
#pragma unroll
                for (int j = 0; j < 4; j++) {
                    bf16x8 bv = Bf[q * 129 + n0 + j * 16 + l15];
#pragma unroll
                    for (int i = 0; i < 4; i++)
                        acc[i][j] = __builtin_amdgcn_mfma_f32_16x16x32_bf16(av[i], bv, acc[i][j], 0, 0, 0);
                }
            }
        }
    }

    // ---- epilogue: BN partial sums ----
    __syncthreads();
    if (t < 256) { red0[t] = 0.f; red1[t] = 0.f; }
    __syncthreads();
#pragma unroll
    for (int i = 0; i < 4; i++) {
#pragma unroll
        for (int r = 0; r < 4; r++) {
            int o_loc = m0 + i * 16 + q * 4 + r;
            float s = 0.f, s2 = 0.f;
#pragma unroll
            for (int j = 0; j < 4; j++) { float v = acc[i][j][r]; s += v; s2 += v * v; }
            s  += __shfl_xor(s, 1);  s  += __shfl_xor(s, 2);  s  += __shfl_xor(s, 4);  s  += __shfl_xor(s, 8);
            s2 += __shfl_xor(s2, 1); s2 += __shfl_xor(s2, 2); s2 += __shfl_xor(s2, 4); s2 += __shfl_xor(s2, 8);
            if (l15 == 0) { atomicAdd(&red0[o_loc], s); atomicAdd(&red1[o_loc], s2); }
        }
    }
    __syncthreads();
    if (t < 256) {
        atomicAdd(&stats[t], red0[t]);
        atomicAdd(&stats[256 + t], red1[t]);
    }

    // ---- epilogue: C write via LDS slab (full-line 512B row stores) ----
    float* outb = out + ((size_t)b * O_) * HW_ + (size_t)h * W_;
#pragma unroll
    for (int i = 0; i < 4; i++) {
        __syncthreads();
        int o_rel_base = (wv & 3) * 16 + q * 4;     // + r
        int col_base = ph * 64 + l15;               // + j*16
#pragma unroll
        for (int j = 0; j < 4; j++)
#pragma unroll
            for (int r = 0; r < 4; r++)
                slab[(o_rel_base + r) * 132 + col_base + j * 16] = acc[i][j][r];
        __syncthreads();
#pragma unroll
        for (int pass = 0; pass < 4; pass++) {
            int f = pass * 512 + t;
            int ro = f >> 5, c4 = f & 31;
            int o = ((ro >> 4) << 6) + i * 16 + (ro & 15);
            float4 v = *(float4*)&slab[ro * 132 + c4 * 4];
            *(float4*)&outb[(size_t)o * HW_ + c4 * 4] = v;
        }
    }
}

// ---------------- K4: BN stats finalize ----------------
__global__ void k_bnstats(float* __restrict__ stats,
                          const float* __restrict__ gamma,
                          const float* __restrict__ beta) {
    int t = threadIdx.x;  // 256
    float s = stats[t], s2 = stats[256 + t];
    float mean = s * (1.f / 65536.f);
    float var = s2 * (1.f / 65536.f) - mean * mean;
    float sc = gamma[t] * rsqrtf(var + 1e-5f);
    float sh = beta[t] - mean * sc;
    stats[512 + t] = sc;
    stats[768 + t] = sh;
}

// ---------------- K5: normalize + leaky ReLU (in-place on d_out) ----------------
__global__ __launch_bounds__(256) void k_apply(float* __restrict__ out,
                                               const float* __restrict__ stats) {
    int idx = blockIdx.x * 256 + threadIdx.x;
    int e = idx * 4;
    int o = (e >> 14) & 255;
    float sc = stats[512 + o], sh = stats[768 + o];
    float4 v = *(float4*)(out + e);
    v.x = v.x * sc + sh; v.x = (v.x >= 0.f) ? v.x : 0.1f * v.x;
    v.y = v.y * sc + sh; v.y = (v.y >= 0.f) ? v.y : 0.1f * v.y;
    v.z = v.z * sc + sh; v.z = (v.z >= 0.f) ? v.z : 0.1f * v.z;
    v.w = v.w * sc + sh; v.w = (v.w >= 0.f) ? v.w : 0.1f * v.w;
    *(float4*)(out + e) = v;
}

extern "C" void kernel_launch(void* const* d_in, const int* in_sizes, int n_in,
                              void* d_out, int out_size, void* d_ws, size_t ws_size,
                              hipStream_t stream) {
    const float* x      = (const float*)d_in[0];
    const float* p_w    = (const float*)d_in[1];
    const float* p_b    = (const float*)d_in[2];
    const float* w_conv = (const float*)d_in[3];
    const float* gamma  = (const float*)d_in[4];
    const float* beta   = (const float*)d_in[5];
    float* out = (float*)d_out;

    char* wsb = (char*)d_ws;
    unsigned short* xpad  = (unsigned short*)wsb;
    float*          offT  = (float*)(wsb + OFF_BYTE);
    unsigned short* wrepb = (unsigned short*)(wsb + WREPB_BYTE);
    float*          stats = (float*)(wsb + STATS_BYTE);
    short*          wofff = (short*)(wsb + WOFF_BYTE);

    hipMemsetAsync(xpad, 0, (size_t)XPAD_BYTES, stream);
    hipMemsetAsync(stats, 0, 4096, stream);

    k_transpose<<<dim3(W_ / 32, C_ / 32, B_ * H_), dim3(32, 8), 0, stream>>>(x, xpad);
    k_repack2<<<dim3(144), 256, 0, stream>>>(p_w, wofff);
    k_offconv<<<dim3(2, H_, B_), 256, 0, stream>>>(xpad, wofff, p_b, offT);
    k_repack<<<dim3((9 * C_ * O_ + 255) / 256), 256, 0, stream>>>(w_conv, wrepb);
    k_main<<<dim3(512), 512, 0, stream>>>(xpad, offT, wrepb, out, stats);
    k_bnstats<<<1, 256, 0, stream>>>(stats, gamma, beta);
    k_apply<<<dim3(16384), 256, 0, stream>>>(out, stats);
}